// Round 17
// baseline (307.472 us; speedup 1.0000x reference)
//
#include <hip/hip_runtime.h>
#include <hip/hip_bf16.h>
#include <stdint.h>
#include <stddef.h>

using bf16 = __hip_bfloat16;

typedef __attribute__((ext_vector_type(4))) float f32x4;
typedef __attribute__((ext_vector_type(8))) short bf16x8;
typedef __attribute__((ext_vector_type(4))) unsigned short u16x4;

#define K_DIM 4096
#define M_ROWS 8192
#define BM 256
#define BN 256
#define BK 64
#define NT (K_DIM / BK)      // 64 K-tiles
#define MT2 (M_ROWS / BM)    // 32
#define NT2 (K_DIM / BN)     // 16

template<int M> struct MC { static constexpr int value = M; };

// ---------------------------------------------------------------------------
// Kernel 1: f32 -> bf16 conversion (vectorized, grid-stride)
// ---------------------------------------------------------------------------
__global__ void conv_bf16(const float* __restrict__ in, bf16* __restrict__ outb, int n4) {
  int idx = blockIdx.x * blockDim.x + threadIdx.x;
  int stride = gridDim.x * blockDim.x;
  for (int k = idx; k < n4; k += stride) {
    f32x4 v = ((const f32x4*)in)[k];
    bf16 tmp[4];
    tmp[0] = __float2bfloat16(v.x);
    tmp[1] = __float2bfloat16(v.y);
    tmp[2] = __float2bfloat16(v.z);
    tmp[3] = __float2bfloat16(v.w);
    ((u16x4*)outb)[k] = *(const u16x4*)tmp;
  }
}

// ---------------------------------------------------------------------------
// Kernel 2: build G^T in bf16 (verified round 1).
// ---------------------------------------------------------------------------
__global__ void build_gt(const float* __restrict__ core0, const float* __restrict__ core1,
                         bf16* __restrict__ GT) {
  int j = blockIdx.x >> 6;
  int i = blockIdx.x & 63;
  __shared__ float c0s[64][16];
  __shared__ float c1s[64][16];
  int t = threadIdx.x;
#pragma unroll
  for (int rep = 0; rep < 4; ++rep) {
    int idx = rep * 256 + t;
    int row = idx >> 4;
    int b = idx & 15;
    size_t base = ((size_t)(j * 64 + row) * 64 + i) * 16 + b;
    c1s[row][b] = core1[base];
    c0s[row][b] = core0[base];
  }
  __syncthreads();
  int x = t & 63;
  int ys = t >> 6;
  float r1[16];
#pragma unroll
  for (int b = 0; b < 16; ++b) r1[b] = c1s[x][b];
#pragma unroll
  for (int yy = 0; yy < 16; ++yy) {
    int y = ys * 16 + yy;
    float acc = 0.f;
#pragma unroll
    for (int b = 0; b < 16; ++b) acc += r1[b] * c0s[y][b];
    GT[((size_t)(y * 64 + i) << 12) + (size_t)(j * 64 + x)] = __float2bfloat16(acc);
  }
}

// ---------------------------------------------------------------------------
// Kernel 3: R16 lag-1 schedule with the prologue race FIXED (restored
// VMCNT4+BARRIER before tile 0 — certifies ALL waves' tile-0 staging landed
// before any wave's first LDS read; R16's NaN came from reading LDS rows
// whose staging loads a slower wave had not yet issued).
// Reads 12/4/8/0 per phase; MFMAs lag one phase: ph0 Q11(t-1), ph1 Q00(t),
// ph2 Q01(t), ph3 Q10(t) — each read batch drains UNDER an MFMA burst.
// Two asm fences/tile: lgkm(8) pre-barrier @ph2, lgkm(0) pre-barrier @ph3.
// vmcnt(4)/tile at ph0. Stages at phase END (post-MFMA).
// ---------------------------------------------------------------------------
__device__ __forceinline__ void gload_lds16(const bf16* g, bf16* l) {
  __builtin_amdgcn_global_load_lds(
      (const __attribute__((address_space(1))) unsigned int*)(g),
      (__attribute__((address_space(3))) unsigned int*)(l),
      16, 0, 0);
}

#define BARRIER() asm volatile("s_barrier" ::: "memory")
#define SCHED0() __builtin_amdgcn_sched_barrier(0)
#define LGKM8() asm volatile("s_waitcnt lgkmcnt(8)" ::: "memory")
#define LGKM0() asm volatile("s_waitcnt lgkmcnt(0)" ::: "memory")
#define SP1() __builtin_amdgcn_s_setprio(1)
#define SP0() __builtin_amdgcn_s_setprio(0)
#define VMCNT4() asm volatile("s_waitcnt vmcnt(4)" ::: "memory")
#define VMCNT0() asm volatile("s_waitcnt vmcnt(0)" ::: "memory")

__global__ __launch_bounds__(512, 2)
void gemm_xg(const bf16* __restrict__ Xb, const bf16* __restrict__ GT,
             const float* __restrict__ bias, float* __restrict__ out) {
  __shared__ bf16 As[2][BM * BK];   // 2 x 32 KiB
  __shared__ bf16 Bs[2][BN * BK];   // 2 x 32 KiB

  // XCD-aware swizzle: nwg = 512, divisible by 8
  int bid = blockIdx.x;
  int sb = (bid & 7) * (MT2 * NT2 / 8) + (bid >> 3);
  int bm = sb >> 4;
  int bn = sb & 15;

  int t = threadIdx.x;
  int lane = t & 63;
  int wid = t >> 6;

  // ---- staging addressing (linear LDS dest, inverse-swizzled global src) ----
  int srow = t >> 3;                    // 0..63
  int scol = t & 7;                     // dest 16B slot (linear)
  int sxor = scol ^ (srow & 7);         // pre-swizzled global slot
  const bf16* gA0 = Xb + ((size_t)(bm * BM + srow) * K_DIM) + sxor * 8;
  const bf16* gB0 = GT + ((size_t)(bn * BN + srow) * K_DIM) + sxor * 8;
  int lbase = srow * BK + scol * 8;

  auto sA = [&](int buf, int h, int kt) {
    const bf16* g = gA0 + (size_t)(h * 128) * K_DIM + (size_t)kt * BK;
    bf16* l = &As[buf][h * 128 * BK + lbase];
    gload_lds16(g, l);
    gload_lds16(g + (size_t)64 * K_DIM, l + 64 * BK);
  };
  auto sB = [&](int buf, int h, int kt) {
    const bf16* g = gB0 + (size_t)(h * 128) * K_DIM + (size_t)kt * BK;
    bf16* l = &Bs[buf][h * 128 * BK + lbase];
    gload_lds16(g, l);
    gload_lds16(g + (size_t)64 * K_DIM, l + 64 * BK);
  };

  // ---- fragment addressing (swizzled ds_read; verbatim R15) ----
  int wm = wid >> 2;        // 0..1
  int wn = wid & 3;         // 0..3
  int lr = lane & 15;
  int g4 = lane >> 4;
  int x7 = lr & 7;
  int swk0 = ((g4 ^ x7) << 3);
  int swk1 = (((4 + g4) ^ x7) << 3);
  int abase = (wm * 128 + lr) * BK;
  int bbase = (wn * 64 + lr) * BK;

  f32x4 acc[8][4] = {};
  bf16x8 a0[4][2], a1[4][2];   // A-MH0 / A-MH1 of current tile
  bf16x8 b0[2][2], b1[2][2];   // B-NH0 / B-NH1 of current tile

  auto rdA0 = [&](const bf16* Ap) {
#pragma unroll
    for (int mi = 0; mi < 4; ++mi) {
      int off = abase + mi * 1024;
      a0[mi][0] = *(const bf16x8*)&Ap[off + swk0];
      a0[mi][1] = *(const bf16x8*)&Ap[off + swk1];
    }
  };
  auto rdA1 = [&](const bf16* Ap) {
#pragma unroll
    for (int mi = 0; mi < 4; ++mi) {
      int off = abase + (4 + mi) * 1024;
      a1[mi][0] = *(const bf16x8*)&Ap[off + swk0];
      a1[mi][1] = *(const bf16x8*)&Ap[off + swk1];
    }
  };
  auto rdB0 = [&](const bf16* Bp) {
#pragma unroll
    for (int ni = 0; ni < 2; ++ni) {
      int off = bbase + ni * 1024;
      b0[ni][0] = *(const bf16x8*)&Bp[off + swk0];
      b0[ni][1] = *(const bf16x8*)&Bp[off + swk1];
    }
  };
  auto rdB1 = [&](const bf16* Bp) {
#pragma unroll
    for (int ni = 0; ni < 2; ++ni) {
      int off = bbase + (2 + ni) * 1024;
      b1[ni][0] = *(const bf16x8*)&Bp[off + swk0];
      b1[ni][1] = *(const bf16x8*)&Bp[off + swk1];
    }
  };
  auto MQ = [&](int mh, int nh, bf16x8 (&av)[4][2], bf16x8 (&bv)[2][2]) {
#pragma unroll
    for (int kk = 0; kk < 2; ++kk)
#pragma unroll
      for (int mi = 0; mi < 4; ++mi)
#pragma unroll
        for (int ni = 0; ni < 2; ++ni)
          acc[mh * 4 + mi][nh * 2 + ni] = __builtin_amdgcn_mfma_f32_16x16x32_bf16(
              av[mi][kk], bv[ni][kk], acc[mh * 4 + mi][nh * 2 + ni], 0, 0, 0);
  };

  const bf16* Ap0 = &As[0][0];
  const bf16* Bp0 = &Bs[0][0];
  const bf16* Ap1 = &As[1][0];
  const bf16* Bp1 = &Bs[1][0];

  // ---- per-tile; MODE: 0=first, 1=steady, 2=t==NT-2 (no sB), 3=last ----
  auto tile = [&](int kt, int cur, auto modec) {
    constexpr int MODE = decltype(modec)::value;
    const bf16* Ac = cur ? Ap1 : Ap0;
    const bf16* Bc = cur ? Bp1 : Bp0;
    const int nb = cur ^ 1;

    // ph0: reads A0,B0 (12); MFMA Q11(t-1); stage A(t+1)h0
    if (MODE == 3) { VMCNT0(); } else { VMCNT4(); }  // retire B(t),A(t); keep B(t+1)
    rdA0(Ac);
    rdB0(Bc);
    BARRIER(); SCHED0();
    if (MODE != 0) { SP1(); MQ(1, 1, a1, b1); SP0(); }  // reads drain under this
    if (MODE < 3) sA(nb, 0, kt + 1);

    // ph1: reads B1 (4); MFMA Q00(t); stage A(t+1)h1
    rdB1(Bc);
    BARRIER(); SCHED0();
    SP1(); MQ(0, 0, a0, b0); SP0();     // compiler-counted wait drains ph0's 12
    if (MODE < 3) sA(nb, 1, kt + 1);

    // ph2: reads A1 (8); lgkm(8) pre-barrier (certifies B1 drained -> B-buf
    //      WAR closed before ph2/ph3-end stages); MFMA Q01(t); stage B(t+2)h0
    rdA1(Ac);
    LGKM8();
    BARRIER(); SCHED0();
    SP1(); MQ(0, 1, a0, b1); SP0();     // own A1 reads drain under this
    if (MODE <= 1) sB(cur, 0, kt + 2);

    // ph3: lgkm(0) pre-barrier (A1 drained -> A-buf WAR closed + Q10/Q11
    //      operands certified); MFMA Q10(t); stage B(t+2)h1
    LGKM0();
    BARRIER(); SCHED0();
    SP1(); MQ(1, 0, a1, b0); SP0();
    if (MODE <= 1) sB(cur, 1, kt + 2);
  };

  // ---- prologue: FIFO order B(0), A(0), B(1); THEN certify tile-0 landed
  //      for ALL waves (vmcnt(4) retires B(0),A(0); barrier propagates) ----
  sB(0, 0, 0); sB(0, 1, 0);
  sA(0, 0, 0); sA(0, 1, 0);
  sB(1, 0, 1); sB(1, 1, 1);
  VMCNT4();
  BARRIER();

  tile(0, 0, MC<0>{});
  tile(1, 1, MC<1>{});
#pragma unroll 1
  for (int i = 1; i < NT / 2 - 1; ++i) {
    tile(2 * i,     0, MC<1>{});
    tile(2 * i + 1, 1, MC<1>{});
  }
  tile(NT - 2, 0, MC<2>{});
  tile(NT - 1, 1, MC<3>{});

  // trailing Q11 of tile NT-1 (operands certified by ph3's lgkm(0))
  SP1(); MQ(1, 1, a1, b1); SP0();

  // ---- epilogue: C/D layout col = lane&15, row = (lane>>4)*4 + r ----
  int colbase = bn * BN + wn * 64 + lr;
  int rowbase = bm * BM + wm * 128 + g4 * 4;
#pragma unroll
  for (int ni = 0; ni < 4; ++ni) {
    int col = colbase + ni * 16;
    float bv = bias[col];
#pragma unroll
    for (int mi = 0; mi < 8; ++mi) {
#pragma unroll
      for (int r = 0; r < 4; ++r) {
        int row = rowbase + mi * 16 + r;
        out[(size_t)row * K_DIM + col] = acc[mi][ni][r] + bv;
      }
    }
  }
}

// ---------------------------------------------------------------------------
extern "C" void kernel_launch(void* const* d_in, const int* in_sizes, int n_in,
                              void* d_out, int out_size, void* d_ws, size_t ws_size,
                              hipStream_t stream) {
  const float* x     = (const float*)d_in[0];
  const float* core0 = (const float*)d_in[1];
  const float* core1 = (const float*)d_in[2];
  const float* bias  = (const float*)d_in[3];
  float* out = (float*)d_out;

  bf16* Xb = (bf16*)d_ws;
  bf16* GT = (bf16*)((char*)d_ws + (size_t)M_ROWS * K_DIM * sizeof(bf16));

  conv_bf16<<<2048, 256, 0, stream>>>(x, Xb, (M_ROWS * K_DIM) / 4);
  build_gt<<<4096, 256, 0, stream>>>(core0, core1, GT);
  gemm_xg<<<MT2 * NT2, 512, 0, stream>>>(Xb, GT, bias, out);
}

// Round 18
// 285.500 us; speedup vs baseline: 1.0770x; 1.0770x over previous
//
#include <hip/hip_runtime.h>
#include <hip/hip_bf16.h>
#include <stdint.h>
#include <stddef.h>

using bf16 = __hip_bfloat16;

typedef __attribute__((ext_vector_type(4))) float f32x4;
typedef __attribute__((ext_vector_type(8))) short bf16x8;
typedef __attribute__((ext_vector_type(4))) unsigned short u16x4;

#define K_DIM 4096
#define M_ROWS 8192
#define BM 256
#define BN 256
#define BK 64
#define NT (K_DIM / BK)      // 64 K-tiles
#define MT2 (M_ROWS / BM)    // 32
#define NT2 (K_DIM / BN)     // 16

template<int M> struct MC { static constexpr int value = M; };

// ---------------------------------------------------------------------------
// Kernel 1: f32 -> bf16 conversion (vectorized, grid-stride)
// ---------------------------------------------------------------------------
__global__ void conv_bf16(const float* __restrict__ in, bf16* __restrict__ outb, int n4) {
  int idx = blockIdx.x * blockDim.x + threadIdx.x;
  int stride = gridDim.x * blockDim.x;
  for (int k = idx; k < n4; k += stride) {
    f32x4 v = ((const f32x4*)in)[k];
    bf16 tmp[4];
    tmp[0] = __float2bfloat16(v.x);
    tmp[1] = __float2bfloat16(v.y);
    tmp[2] = __float2bfloat16(v.z);
    tmp[3] = __float2bfloat16(v.w);
    ((u16x4*)outb)[k] = *(const u16x4*)tmp;
  }
}

// ---------------------------------------------------------------------------
// Kernel 2: build G^T in bf16 (verified round 1).
// ---------------------------------------------------------------------------
__global__ void build_gt(const float* __restrict__ core0, const float* __restrict__ core1,
                         bf16* __restrict__ GT) {
  int j = blockIdx.x >> 6;
  int i = blockIdx.x & 63;
  __shared__ float c0s[64][16];
  __shared__ float c1s[64][16];
  int t = threadIdx.x;
#pragma unroll
  for (int rep = 0; rep < 4; ++rep) {
    int idx = rep * 256 + t;
    int row = idx >> 4;
    int b = idx & 15;
    size_t base = ((size_t)(j * 64 + row) * 64 + i) * 16 + b;
    c1s[row][b] = core1[base];
    c0s[row][b] = core0[base];
  }
  __syncthreads();
  int x = t & 63;
  int ys = t >> 6;
  float r1[16];
#pragma unroll
  for (int b = 0; b < 16; ++b) r1[b] = c1s[x][b];
#pragma unroll
  for (int yy = 0; yy < 16; ++yy) {
    int y = ys * 16 + yy;
    float acc = 0.f;
#pragma unroll
    for (int b = 0; b < 16; ++b) acc += r1[b] * c0s[y][b];
    GT[((size_t)(y * 64 + i) << 12) + (size_t)(j * 64 + x)] = __float2bfloat16(acc);
  }
}

// ---------------------------------------------------------------------------
// Kernel 3 (CHAMPION, R15): 256x256 / BK=64 / 8-wave, phase order
//   reads -> stage -> lgkm(0) -> barrier -> MFMA(regs-only)
// 1 barrier/phase (ph3 none). lgkm(0) BEFORE the barrier closes the
// cross-wave read-vs-stage race; MFMA after the barrier is register-only.
// vmcnt(4)/tile at ph0 (drains A(t),B(t); keeps B(t+1) in flight).
// Measured: GEMM 263 us, 1045 TF, MfmaUtil 46.9%, bank conflicts 0.
// ---------------------------------------------------------------------------
__device__ __forceinline__ void gload_lds16(const bf16* g, bf16* l) {
  __builtin_amdgcn_global_load_lds(
      (const __attribute__((address_space(1))) unsigned int*)(g),
      (__attribute__((address_space(3))) unsigned int*)(l),
      16, 0, 0);
}

template<int MH>
__device__ __forceinline__ void read_a(bf16x8 (&af)[4][2], const bf16* As,
                                       int abase, int swk0, int swk1) {
#pragma unroll
  for (int mi = 0; mi < 4; ++mi) {
    int off = abase + (MH * 4 + mi) * 1024;   // 16 rows * 64 elem
    af[mi][0] = *(const bf16x8*)&As[off + swk0];
    af[mi][1] = *(const bf16x8*)&As[off + swk1];
  }
}

template<int NH>
__device__ __forceinline__ void read_b(bf16x8 (&bfr)[4][2], const bf16* Bs,
                                       int bbase, int swk0, int swk1) {
#pragma unroll
  for (int ni = 0; ni < 2; ++ni) {
    int off = bbase + (NH * 2 + ni) * 1024;
    bfr[NH * 2 + ni][0] = *(const bf16x8*)&Bs[off + swk0];
    bfr[NH * 2 + ni][1] = *(const bf16x8*)&Bs[off + swk1];
  }
}

template<int MH, int NH>
__device__ __forceinline__ void mfma_quad(f32x4 (&acc)[8][4], const bf16x8 (&af)[4][2],
                                          const bf16x8 (&bfr)[4][2]) {
#pragma unroll
  for (int kk = 0; kk < 2; ++kk)
#pragma unroll
    for (int mi = 0; mi < 4; ++mi)
#pragma unroll
      for (int ni = 0; ni < 2; ++ni)
        acc[MH * 4 + mi][NH * 2 + ni] = __builtin_amdgcn_mfma_f32_16x16x32_bf16(
            af[mi][kk], bfr[NH * 2 + ni][kk], acc[MH * 4 + mi][NH * 2 + ni], 0, 0, 0);
}

#define BARRIER() asm volatile("s_barrier" ::: "memory")
#define LGKM0() asm volatile("s_waitcnt lgkmcnt(0)" ::: "memory")
#define SP1() __builtin_amdgcn_s_setprio(1)
#define SP0() __builtin_amdgcn_s_setprio(0)
#define VMCNT4() asm volatile("s_waitcnt vmcnt(4)" ::: "memory")
#define VMCNT0() asm volatile("s_waitcnt vmcnt(0)" ::: "memory")

__global__ __launch_bounds__(512, 2)
void gemm_xg(const bf16* __restrict__ Xb, const bf16* __restrict__ GT,
             const float* __restrict__ bias, float* __restrict__ out) {
  __shared__ bf16 As[2][BM * BK];   // 2 x 32 KiB
  __shared__ bf16 Bs[2][BN * BK];   // 2 x 32 KiB

  // XCD-aware swizzle: nwg = 512, divisible by 8
  int bid = blockIdx.x;
  int sb = (bid & 7) * (MT2 * NT2 / 8) + (bid >> 3);
  int bm = sb >> 4;
  int bn = sb & 15;

  int t = threadIdx.x;
  int lane = t & 63;
  int wid = t >> 6;

  // ---- staging addressing (linear LDS dest, inverse-swizzled global src) ----
  int srow = t >> 3;                    // 0..63
  int scol = t & 7;                     // dest 16B slot (linear)
  int sxor = scol ^ (srow & 7);         // pre-swizzled global slot
  const bf16* gA0 = Xb + ((size_t)(bm * BM + srow) * K_DIM) + sxor * 8;
  const bf16* gB0 = GT + ((size_t)(bn * BN + srow) * K_DIM) + sxor * 8;
  int lbase = srow * BK + scol * 8;

  auto sA = [&](int buf, int h, int kt) {
    const bf16* g = gA0 + (size_t)(h * 128) * K_DIM + (size_t)kt * BK;
    bf16* l = &As[buf][h * 128 * BK + lbase];
    gload_lds16(g, l);
    gload_lds16(g + (size_t)64 * K_DIM, l + 64 * BK);
  };
  auto sB = [&](int buf, int h, int kt) {
    const bf16* g = gB0 + (size_t)(h * 128) * K_DIM + (size_t)kt * BK;
    bf16* l = &Bs[buf][h * 128 * BK + lbase];
    gload_lds16(g, l);
    gload_lds16(g + (size_t)64 * K_DIM, l + 64 * BK);
  };

  // ---- fragment addressing (swizzled ds_read) ----
  int wm = wid >> 2;        // 0..1
  int wn = wid & 3;         // 0..3
  int lr = lane & 15;
  int g4 = lane >> 4;
  int x7 = lr & 7;
  int swk0 = ((g4 ^ x7) << 3);
  int swk1 = (((4 + g4) ^ x7) << 3);
  int abase = (wm * 128 + lr) * BK;
  int bbase = (wn * 64 + lr) * BK;

  f32x4 acc[8][4] = {};
  bf16x8 af[4][2];
  bf16x8 bfr[4][2];

  const bf16* Ab[2] = { &As[0][0], &As[1][0] };
  const bf16* Bb[2] = { &Bs[0][0], &Bs[1][0] };

  // ---- per-tile; MODE: 0=steady, 1=t==NT-2 (skip B stages), 2=last ----
  auto tile = [&](int kt, int cur, auto modec) {
    constexpr int MODE = decltype(modec)::value;
    const bf16* Ac = Ab[cur];
    const bf16* Bc = Bb[cur];
    const int nb = cur ^ 1;

    // ph0: Q00 — reads A0(t)+B0(t); stage A(t+1)h0; lgkm; barrier; MFMA
    if (MODE == 2) { VMCNT0(); } else { VMCNT4(); }   // drain A(t),B(t); keep B(t+1)
    read_a<0>(af, Ac, abase, swk0, swk1);
    read_b<0>(bfr, Bc, bbase, swk0, swk1);
    if (MODE < 2) sA(nb, 0, kt + 1);
    LGKM0();
    BARRIER();
    SP1(); mfma_quad<0, 0>(acc, af, bfr); SP0();

    // ph1: Q01 — reads B1(t); stage A(t+1)h1
    read_b<1>(bfr, Bc, bbase, swk0, swk1);
    if (MODE < 2) sA(nb, 1, kt + 1);
    LGKM0();
    BARRIER();
    SP1(); mfma_quad<0, 1>(acc, af, bfr); SP0();

    // ph2: Q10 — reads A1(t); stage B(t+2)h0
    read_a<1>(af, Ac, abase, swk0, swk1);
    if (MODE == 0) sB(cur, 0, kt + 2);
    LGKM0();
    BARRIER();
    SP1(); mfma_quad<1, 0>(acc, af, bfr); SP0();

    // ph3: Q11 — no reads; stage B(t+2)h1; no barrier needed (audited)
    if (MODE == 0) sB(cur, 1, kt + 2);
    SP1(); mfma_quad<1, 1>(acc, af, bfr); SP0();
  };

  // ---- prologue: FIFO order B(0), A(0), B(1); drain tile0, keep B(1) ----
  sB(0, 0, 0); sB(0, 1, 0);
  sA(0, 0, 0); sA(0, 1, 0);
  sB(1, 0, 1); sB(1, 1, 1);
  VMCNT4();
  BARRIER();

#pragma unroll 1
  for (int i = 0; i < NT / 2 - 1; ++i) {
    tile(2 * i,     0, MC<0>{});
    tile(2 * i + 1, 1, MC<0>{});
  }
  tile(NT - 2, 0, MC<1>{});
  tile(NT - 1, 1, MC<2>{});

  // ---- epilogue: C/D layout col = lane&15, row = (lane>>4)*4 + r ----
  int colbase = bn * BN + wn * 64 + lr;
  int rowbase = bm * BM + wm * 128 + g4 * 4;
#pragma unroll
  for (int ni = 0; ni < 4; ++ni) {
    int col = colbase + ni * 16;
    float bv = bias[col];
#pragma unroll
    for (int mi = 0; mi < 8; ++mi) {
#pragma unroll
      for (int r = 0; r < 4; ++r) {
        int row = rowbase + mi * 16 + r;
        out[(size_t)row * K_DIM + col] = acc[mi][ni][r] + bv;
      }
    }
  }
}

// ---------------------------------------------------------------------------
extern "C" void kernel_launch(void* const* d_in, const int* in_sizes, int n_in,
                              void* d_out, int out_size, void* d_ws, size_t ws_size,
                              hipStream_t stream) {
  const float* x     = (const float*)d_in[0];
  const float* core0 = (const float*)d_in[1];
  const float* core1 = (const float*)d_in[2];
  const float* bias  = (const float*)d_in[3];
  float* out = (float*)d_out;

  bf16* Xb = (bf16*)d_ws;
  bf16* GT = (bf16*)((char*)d_ws + (size_t)M_ROWS * K_DIM * sizeof(bf16));

  conv_bf16<<<2048, 256, 0, stream>>>(x, Xb, (M_ROWS * K_DIM) / 4);
  build_gt<<<4096, 256, 0, stream>>>(core0, core1, GT);
  gemm_xg<<<MT2 * NT2, 512, 0, stream>>>(Xb, GT, bias, out);
}